// Round 8
// baseline (150.693 us; speedup 1.0000x reference)
//
#include <hip/hip_runtime.h>
#include <hip/hip_bf16.h>

#define NN 8192
#define BM 32
#define BK 256
#define XWF 304           // per-tile f32 window length (288 used, padded)

typedef short bfrag8 __attribute__((ext_vector_type(8)));   // 8 bf16 in 4 VGPRs
typedef float floatx4 __attribute__((ext_vector_type(4)));

static __device__ __forceinline__ unsigned short f2bf(float f) {
  unsigned u = __builtin_bit_cast(unsigned, f);
  u = (u + 0x7FFFu + ((u >> 16) & 1u)) >> 16;   // RNE
  return (unsigned short)u;
}
static __device__ __forceinline__ unsigned cvt_pk_bf16(float a, float b) {
  return (unsigned)f2bf(a) | ((unsigned)f2bf(b) << 16);
}
// truncation pack (bf16): lo16 = a.hi16, hi16 = b.hi16 — 2 VALU ops
static __device__ __forceinline__ unsigned trunc_pk_bf16(float a, float b) {
  unsigned ua = __builtin_bit_cast(unsigned, a);
  unsigned ub = __builtin_bit_cast(unsigned, b);
  return (ub & 0xFFFF0000u) | (ua >> 16);
}
static __device__ __forceinline__ float elu(float v) {
  return v > 0.f ? v : expm1f(v);
}

// ---------------- prep: W1^T bf16, W2^T bf16, regu sums --------------------
__global__ void prep_kernel(const float* __restrict__ x, const float* __restrict__ W1,
                            const float* __restrict__ W2, const float* __restrict__ rlen,
                            unsigned short* __restrict__ W1T, unsigned short* __restrict__ W2T,
                            float* __restrict__ acc) {
  const int b = blockIdx.x, t = threadIdx.x;
  if (b < 128) {
    // transpose a 64x64 tile of W1 (8192x64) -> W1T (64x8192) bf16
    __shared__ float tile[64][65];
    const int k0 = b * 64;
#pragma unroll
    for (int it = 0; it < 16; ++it) {
      int k = it * 4 + (t >> 6);
      tile[k][t & 63] = W1[(k0 + k) * 64 + (t & 63)];
    }
    __syncthreads();
#pragma unroll
    for (int it = 0; it < 16; ++it) {
      int f = it * 4 + (t >> 6);
      int kk = t & 63;
      W1T[f * NN + k0 + kk] = f2bf(tile[kk][f]);
    }
  } else if (b == 128) {
    for (int idx = t; idx < 64 * 64; idx += 256) {
      int k = idx >> 6, f = idx & 63;
      W2T[f * 64 + k] = f2bf(W2[idx]);
    }
  } else {
    // blocks 129,130: x2 = sum_c x^2; s1 = sum x2, s2 = sum exp(x2/(2 L^2))
    float rl = rlen[0];
    float inv = 1.f / (2.f * rl * rl);
    int base = (b - 129) * 4096;
    float s1 = 0.f, s2 = 0.f;
    for (int ii = 0; ii < 16; ++ii) {
      int i = base + ii * 256 + t;
      float a0 = x[i], a1 = x[NN + i], a2 = x[2 * NN + i];
      float s = a0 * a0 + a1 * a1 + a2 * a2;
      s1 += s; s2 += expf(s * inv);
    }
    for (int d = 32; d > 0; d >>= 1) { s1 += __shfl_down(s1, d); s2 += __shfl_down(s2, d); }
    __shared__ float p1[4], p2[4];
    if ((t & 63) == 0) { p1[t >> 6] = s1; p2[t >> 6] = s2; }
    __syncthreads();
    if (t == 0) {
      atomicAdd(&acc[1], p1[0] + p1[1] + p1[2] + p1[3]);
      atomicAdd(&acc[2], p2[0] + p2[1] + p2[2] + p2[3]);
    }
  }
}

// ---------------- main: fused corr formation + MFMA (corr @ W1 partial) ----
// grid 512 = 256 i-tiles x 2 k-halves -> 2 blocks/CU for latency hiding.
// cr: double-buffered bf16 corr tile, rotation-swizzled 16B slots.
// B (W1T rows) prefetched global->VGPR one tile ahead. One barrier/tile.
// Output: partial h1 (f32) per (i-tile, k-half) -> ws, reduced by tail_kernel.
__global__ __launch_bounds__(512, 4) void main_kernel(
    const float* __restrict__ x, const unsigned short* __restrict__ W1T,
    float* __restrict__ part) {
  __shared__ __align__(16) unsigned short cr[2][BM * 256];   // 32 KB
  __shared__ __align__(16) float xwinf[2][3][XWF];           // 7.3 KB

  const int t = threadIdx.x;
  const int ib = blockIdx.x >> 1;   // i-tile
  const int hb = blockIdx.x & 1;    // k-half
  const int i0 = ib * BM;
  const int kt0 = hb * 16;          // first of 16 K-tiles for this block
  const int wv = t >> 6;            // wave id 0..7 = formation row group
  const int l = t & 63;
  const int lg = l >> 4, lr = l & 15;

  // formation coords: wave wv owns rows [wv*4, wv*4+4); lane cg owns 4 cols
  const int cg = l;                 // 0..63, cols [cg*4, cg*4+4)
  const int sb = wv * 4 + cg * 4;   // window base (mult of 4 -> 16B aligned)

  // MFMA wave mapping (verified layout)
  const int np = wv & 1, quad = wv >> 1;
  const unsigned short* bp0 = W1T + (np * 32 + lr) * NN + quad * 32 + lg * 8;
  const unsigned short* bp1 = bp0 + 16 * NN;
  const int koff0 = kt0 * BK;

  // x row values for formation
  float xr[3][4];
#pragma unroll
  for (int c = 0; c < 3; ++c)
#pragma unroll
    for (int r = 0; r < 4; ++r)
      xr[c][r] = x[c * NN + i0 + wv * 4 + r];

  // prologue: stage window for first tile; load B fragments for first tile
  if (t < 216) {
    int c = t / 72, rr = t - c * 72;
    *(float4*)&xwinf[0][c][rr * 4] =
        *(const float4*)&x[c * NN + ((i0 + koff0 + rr * 4) & (NN - 1))];
  }
  uint4 bA0 = *(const uint4*)(bp0 + koff0);
  uint4 bA1 = *(const uint4*)(bp1 + koff0);
  uint4 bB0 = *(const uint4*)(bp0 + koff0 + 128);
  uint4 bB1 = *(const uint4*)(bp1 + koff0 + 128);

  floatx4 acc00 = {0.f, 0.f, 0.f, 0.f}, acc01 = {0.f, 0.f, 0.f, 0.f};
  floatx4 acc10 = {0.f, 0.f, 0.f, 0.f}, acc11 = {0.f, 0.f, 0.f, 0.f};

  __syncthreads();

  for (int ktt = 0; ktt < 16; ++ktt) {
    const int buf = ktt & 1;
    const int jn = (kt0 + ktt + 1) * BK;   // next tile base
    const bool more = (ktt + 1 < 16);

    // ---- issue next-tile prefetches (window f32 -> reg, B frags -> reg) ----
    float4 sv;
    int c_st = 0, rr_st = 0;
    const bool do_stage = more && (t < 216);
    if (do_stage) {
      c_st = t / 72; rr_st = t - c_st * 72;
      sv = *(const float4*)&x[c_st * NN + ((i0 + jn + rr_st * 4) & (NN - 1))];
    }
    uint4 nA0, nA1, nB0, nB1;
    if (more) {
      nA0 = *(const uint4*)(bp0 + jn);
      nA1 = *(const uint4*)(bp1 + jn);
      nB0 = *(const uint4*)(bp0 + jn + 128);
      nB1 = *(const uint4*)(bp1 + jn + 128);
    }

    // ---- corr tile formation: 4 rows x 4 cols per thread ----
    float acf[4][4];
#pragma unroll
    for (int r = 0; r < 4; ++r)
#pragma unroll
      for (int j = 0; j < 4; ++j) acf[r][j] = 0.f;
#pragma unroll
    for (int c = 0; c < 3; ++c) {
      const float* wp = &xwinf[buf][c][sb];
      float4 v0 = *(const float4*)(wp);
      float4 v1 = *(const float4*)(wp + 4);
      float wf[7] = {v0.x, v0.y, v0.z, v0.w, v1.x, v1.y, v1.z};
#pragma unroll
      for (int r = 0; r < 4; ++r) {
        float xv = xr[c][r];
#pragma unroll
        for (int j = 0; j < 4; ++j) acf[r][j] = fmaf(xv, wf[r + j], acf[r][j]);
      }
    }
    // swizzled bf16 write (truncation rounding; error << threshold headroom)
#pragma unroll
    for (int r = 0; r < 4; ++r) {
      const int row = wv * 4 + r;
      const int sw = ((cg >> 1) + 4 * row) & 31;
      unsigned u0 = trunc_pk_bf16(acf[r][0], acf[r][1]);
      unsigned u1 = trunc_pk_bf16(acf[r][2], acf[r][3]);
      uint2 q = {u0, u1};
      *(uint2*)((char*)&cr[buf][0] + row * 512 + sw * 16 + (cg & 1) * 8) = q;
    }
    // ---- write staged window for next tile ----
    if (do_stage) *(float4*)&xwinf[buf ^ 1][c_st][rr_st * 4] = sv;

    __syncthreads();

    // ---- MFMA: A from swizzled cr, B from prefetched VGPRs ----
#pragma unroll
    for (int s2 = 0; s2 < 2; ++s2) {
      const int slot = (quad + s2 * 4) * 4 + lg;
      const int swz = (slot + 4 * lr) & 31;   // rows lr and 16+lr share (4*row)&31
      bfrag8 a0 = __builtin_bit_cast(bfrag8,
          *(const uint4*)((const char*)&cr[buf][0] + lr * 512 + swz * 16));
      bfrag8 a1 = __builtin_bit_cast(bfrag8,
          *(const uint4*)((const char*)&cr[buf][0] + (16 + lr) * 512 + swz * 16));
      bfrag8 b0 = __builtin_bit_cast(bfrag8, s2 == 0 ? bA0 : bB0);
      bfrag8 b1 = __builtin_bit_cast(bfrag8, s2 == 0 ? bA1 : bB1);
      acc00 = __builtin_amdgcn_mfma_f32_16x16x32_bf16(a0, b0, acc00, 0, 0, 0);
      acc01 = __builtin_amdgcn_mfma_f32_16x16x32_bf16(a0, b1, acc01, 0, 0, 0);
      acc10 = __builtin_amdgcn_mfma_f32_16x16x32_bf16(a1, b0, acc10, 0, 0, 0);
      acc11 = __builtin_amdgcn_mfma_f32_16x16x32_bf16(a1, b1, acc11, 0, 0, 0);
    }
    bA0 = nA0; bA1 = nA1; bB0 = nB0; bB1 = nB1;
  }

  // ---- combine k-split partial accumulators into h1 (f32, reuses cr[0]) ----
  float* h1buf = (float*)&cr[0][0];   // [32][68]
  for (int q = t; q < 32 * 68; q += 512) h1buf[q] = 0.f;
  __syncthreads();
  {
#pragma unroll
    for (int m = 0; m < 2; ++m)
#pragma unroll
      for (int tn = 0; tn < 2; ++tn) {
        floatx4 a = (m == 0) ? (tn == 0 ? acc00 : acc01) : (tn == 0 ? acc10 : acc11);
#pragma unroll
        for (int r = 0; r < 4; ++r) {
          int row = m * 16 + lg * 4 + r;
          int col = np * 32 + tn * 16 + lr;
          atomicAdd(&h1buf[row * 68 + col], a[r]);
        }
      }
  }
  __syncthreads();

  // ---- write partial h1 slice to global (disjoint per block, no atomics) --
  for (int q = t; q < BM * 64; q += 512) {
    int row = q >> 6, col = q & 63;
    part[hb * (NN * 64) + (i0 + row) * 64 + col] = h1buf[row * 68 + col];
  }
}

// ---------------- tail: h1 = part0+part1, elu -> @W2 -> elu -> @W3 -> sum --
__global__ __launch_bounds__(256, 4) void tail_kernel(
    const float* __restrict__ part, const unsigned short* __restrict__ W2T,
    const float* __restrict__ W3, float* __restrict__ acc) {
  __shared__ float z3p[256];
  __shared__ float bsum[2];
  const int t = threadIdx.x;
  const int w4 = t >> 6, l = t & 63;
  const int lg = l >> 4, lr = l & 15;
  const int m2 = w4 & 1, np2 = w4 >> 1;
  const int i0 = blockIdx.x * 128;

  const float w3a = W3[np2 * 32 + lr];
  const float w3b = W3[np2 * 32 + 16 + lr];

#pragma unroll
  for (int rg = 0; rg < 4; ++rg) {
    const int rbase = i0 + rg * 32;
    floatx4 acc2_0 = {0.f, 0.f, 0.f, 0.f}, acc2_1 = {0.f, 0.f, 0.f, 0.f};
#pragma unroll
    for (int ks2 = 0; ks2 < 2; ++ks2) {
      const int kb = ks2 * 32 + lg * 8;
      const int row = rbase + m2 * 16 + lr;
      const float* p0 = &part[row * 64 + kb];
      const float* p1 = &part[NN * 64 + row * 64 + kb];
      unsigned qa[4];
#pragma unroll
      for (int e = 0; e < 4; ++e) {
        float v0 = elu(p0[2 * e] + p1[2 * e]);
        float v1 = elu(p0[2 * e + 1] + p1[2 * e + 1]);
        qa[e] = cvt_pk_bf16(v0, v1);
      }
      uint4 qv = {qa[0], qa[1], qa[2], qa[3]};
      bfrag8 a2 = __builtin_bit_cast(bfrag8, qv);
#pragma unroll
      for (int tn = 0; tn < 2; ++tn) {
        int col2 = np2 * 32 + tn * 16 + lr;
        bfrag8 b2 = __builtin_bit_cast(bfrag8, *(const uint4*)&W2T[col2 * 64 + kb]);
        if (tn == 0)
          acc2_0 = __builtin_amdgcn_mfma_f32_16x16x32_bf16(a2, b2, acc2_0, 0, 0, 0);
        else
          acc2_1 = __builtin_amdgcn_mfma_f32_16x16x32_bf16(a2, b2, acc2_1, 0, 0, 0);
      }
    }
#pragma unroll
    for (int r = 0; r < 4; ++r) {
      float v = elu(acc2_0[r]) * w3a + elu(acc2_1[r]) * w3b;
      v += __shfl_xor(v, 1); v += __shfl_xor(v, 2);
      v += __shfl_xor(v, 4); v += __shfl_xor(v, 8);
      if (lr == 0)
        z3p[(rg * 32 + m2 * 16 + lg * 4 + r) * 2 + np2] = v;
    }
  }
  __syncthreads();
  if (t < 128) {
    float sv2 = z3p[t * 2] + z3p[t * 2 + 1];
    float z3 = elu(sv2);
    z3 += __shfl_xor(z3, 1); z3 += __shfl_xor(z3, 2); z3 += __shfl_xor(z3, 4);
    z3 += __shfl_xor(z3, 8); z3 += __shfl_xor(z3, 16); z3 += __shfl_xor(z3, 32);
    if ((t & 63) == 0) bsum[t >> 6] = z3;
  }
  __syncthreads();
  if (t == 0) atomicAdd(&acc[0], bsum[0] + bsum[1]);
}

// ---------------- finalize ------------------------------------------------
__global__ void fin_kernel(const float* __restrict__ acc, const float* __restrict__ regu2,
                           const float* __restrict__ regu, float* __restrict__ out) {
  if (threadIdx.x == 0)
    out[0] = acc[0] * (1.f / (float)NN) - regu2[0] * acc[1] - regu[0] * acc[2];
}

extern "C" void kernel_launch(void* const* d_in, const int* in_sizes, int n_in,
                              void* d_out, int out_size, void* d_ws, size_t ws_size,
                              hipStream_t stream) {
  const float* x     = (const float*)d_in[0];
  const float* W1    = (const float*)d_in[1];
  const float* W2    = (const float*)d_in[2];
  const float* W3    = (const float*)d_in[3];
  const float* regu2 = (const float*)d_in[4];
  const float* regu  = (const float*)d_in[5];
  const float* rlen  = (const float*)d_in[6];

  char* ws = (char*)d_ws;
  float* acc            = (float*)ws;                       // [0]=sum z3, [1]=sum x2, [2]=sum exp
  unsigned short* W1T   = (unsigned short*)(ws + 16);       // 64*8192 bf16 = 1 MB
  unsigned short* W2T   = (unsigned short*)(ws + 1048592);  // 64*64 bf16 = 8 KB
  float* part           = (float*)(ws + 1056784);           // 2*8192*64 f32 = 4 MB

  (void)hipMemsetAsync(acc, 0, 16, stream);
  prep_kernel<<<131, 256, 0, stream>>>(x, W1, W2, rlen, W1T, W2T, acc);
  main_kernel<<<512, 512, 0, stream>>>(x, W1T, part);
  tail_kernel<<<64, 256, 0, stream>>>(part, W2T, W3, acc);
  fin_kernel<<<1, 64, 0, stream>>>(acc, regu2, regu, (float*)d_out);
}